// Round 2
// baseline (683.710 us; speedup 1.0000x reference)
//
#include <hip/hip_runtime.h>
#include <math.h>

#define DCOLS 128
#define ROUTIT 6
#define EPS_N 1e-12f

__device__ __forceinline__ float shflx(float v, int mask) {
    return __shfl_xor(v, mask, 64);
}

// L2-normalize each 16-wide capsule of each node row. Wave per node,
// lane l owns cols 2l, 2l+1 (capsule = l/8, 8 lanes per capsule).
__global__ void norm_kernel(const float* __restrict__ x, float* __restrict__ xn, int n) {
    int node = (int)((blockIdx.x * blockDim.x + threadIdx.x) >> 6);
    int lane = threadIdx.x & 63;
    if (node >= n) return;
    float2 v = *reinterpret_cast<const float2*>(x + (size_t)node * DCOLS + 2 * lane);
    float sq = v.x * v.x + v.y * v.y;
    sq += shflx(sq, 1); sq += shflx(sq, 2); sq += shflx(sq, 4);  // 8-lane group = one capsule
    float inv = 1.0f / fmaxf(sqrtf(sq), EPS_N);
    float2 o = make_float2(v.x * inv, v.y * inv);
    *reinterpret_cast<float2*>(xn + (size_t)node * DCOLS + 2 * lane) = o;
}

__global__ void count_kernel(const int* __restrict__ trg, int* __restrict__ counts, int m) {
    int e = blockIdx.x * blockDim.x + threadIdx.x;
    if (e < m) atomicAdd(&counts[trg[e]], 1);
}

// Single-block exclusive scan of counts[0..n) -> offsets[0..n]; also leaves
// the exclusive prefix in counts[] (reused as the scatter cursor).
__global__ void scan_kernel(int* counts, int* offsets, int n, int m) {
    __shared__ int part[1024];
    int tid = threadIdx.x;
    if (tid == 0) offsets[n] = m;
    int chunk = (n + 1023) / 1024;
    int lo = tid * chunk;
    int hi = min(lo + chunk, n);
    int s = 0;
    for (int i = lo; i < hi; ++i) s += counts[i];
    part[tid] = s;
    __syncthreads();
    for (int off = 1; off < 1024; off <<= 1) {
        int t = (tid >= off) ? part[tid - off] : 0;
        __syncthreads();
        part[tid] += t;
        __syncthreads();
    }
    int run = (tid > 0) ? part[tid - 1] : 0;  // exclusive prefix of this chunk
    for (int i = lo; i < hi; ++i) {
        int c = counts[i];
        offsets[i] = run;
        counts[i] = run;  // cursor init for scatter
        run += c;
    }
}

__global__ void scatter_kernel(const int* __restrict__ src, const int* __restrict__ trg,
                               int* cursor, int* __restrict__ elist, int m) {
    int e = blockIdx.x * blockDim.x + threadIdx.x;
    if (e < m) {
        int pos = atomicAdd(&cursor[trg[e]], 1);
        elist[pos] = src[e];
    }
}

// Wave per node. Lane l owns cols (2l, 2l+1).
//   capsule index i = l/8            (8 lanes x 2 cols = 16 cols per capsule)
//   S[j] (j in [0,16)) = sum of c over cols 8j..8j+7 -> lives on lanes 4j..4j+3
//   p term for col c uses S[c % 16]; (2l)%16 = j0 (even), (2l+1)%16 = j0+1
__global__ __launch_bounds__(256) void routing_kernel(
    const float* __restrict__ xn, const int* __restrict__ offsets,
    const int* __restrict__ elist, float* __restrict__ out, int n)
{
    int node = (int)((blockIdx.x * blockDim.x + threadIdx.x) >> 6);
    int lane = threadIdx.x & 63;
    if (node >= n) return;

    float2 xv = *reinterpret_cast<const float2*>(xn + (size_t)node * DCOLS + 2 * lane);
    float ce = xv.x, co = xv.y;   // current c, this lane's two cols

    int e0 = offsets[node];
    int e1 = offsets[node + 1];

    int j0  = (2 * lane) & 15;      // even j for col 2l
    int sl0 = 4 * j0;               // lane holding S[j0]
    int sl1 = 4 * (j0 + 1);         // lane holding S[j0+1]

    for (int t = 0; t < ROUTIT; ++t) {
        // S[j] = sum_{i2<8} c[8j+i2]; reduce pairs then 4-lane groups
        float s = ce + co;
        s += shflx(s, 1); s += shflx(s, 2);
        float Sa = __shfl(s, sl0, 64);
        float Sb = __shfl(s, sl1, 64);

        float acc_e = 0.0f, acc_o = 0.0f;
        for (int e = e0; e < e1; ++e) {
            int u = elist[e];
            float2 z = *reinterpret_cast<const float2*>(xn + (size_t)u * DCOLS + 2 * lane);
            float term = z.x * Sa + z.y * Sb;
            // p[i] = sum over capsule i's 16 cols -> reduce 8-lane group
            term += shflx(term, 1); term += shflx(term, 2); term += shflx(term, 4);
            // softmax over the 8 capsules (one value per 8-lane group):
            float mx = term;
            mx = fmaxf(mx, shflx(mx, 8));
            mx = fmaxf(mx, shflx(mx, 16));
            mx = fmaxf(mx, shflx(mx, 32));
            float ex = __expf(term - mx);
            float zs = ex;
            zs += shflx(zs, 8); zs += shflx(zs, 16); zs += shflx(zs, 32);
            float w = ex / zs;
            acc_e = fmaf(w, z.x, acc_e);
            acc_o = fmaf(w, z.y, acc_o);
        }

        ce = acc_e + xv.x;
        co = acc_o + xv.y;
        if (t < ROUTIT - 1) {
            float sq = ce * ce + co * co;
            sq += shflx(sq, 1); sq += shflx(sq, 2); sq += shflx(sq, 4);
            float inv = 1.0f / fmaxf(sqrtf(sq), EPS_N);
            ce *= inv; co *= inv;
        }
    }

    *reinterpret_cast<float2*>(out + (size_t)node * DCOLS + 2 * lane) = make_float2(ce, co);
}

extern "C" void kernel_launch(void* const* d_in, const int* in_sizes, int n_in,
                              void* d_out, int out_size, void* d_ws, size_t ws_size,
                              hipStream_t stream) {
    const float* x = (const float*)d_in[0];
    const int* ei = (const int*)d_in[1];
    float* out = (float*)d_out;
    int n = in_sizes[0] / DCOLS;
    int m = in_sizes[1] / 2;
    const int* src = ei;
    const int* trg = ei + m;

    char* ws = (char*)d_ws;
    float* xn = (float*)ws;       ws += (size_t)n * DCOLS * sizeof(float);
    int* offsets = (int*)ws;      ws += (size_t)(n + 1) * sizeof(int);
    int* cursor = (int*)ws;       ws += (size_t)n * sizeof(int);
    int* elist = (int*)ws;        ws += (size_t)m * sizeof(int);

    (void)hipMemsetAsync(cursor, 0, (size_t)n * sizeof(int), stream);

    norm_kernel<<<(n + 3) / 4, 256, 0, stream>>>(x, xn, n);
    count_kernel<<<(m + 255) / 256, 256, 0, stream>>>(trg, cursor, m);
    scan_kernel<<<1, 1024, 0, stream>>>(cursor, offsets, n, m);
    scatter_kernel<<<(m + 255) / 256, 256, 0, stream>>>(src, trg, cursor, elist, m);
    routing_kernel<<<(n + 3) / 4, 256, 0, stream>>>(xn, offsets, elist, out, n);
}

// Round 3
// 384.231 us; speedup vs baseline: 1.7794x; 1.7794x over previous
//
#include <hip/hip_runtime.h>
#include <math.h>

#define DCOLS 128
#define ROUTIT 6
#define EPS_N 1e-12f
#define EPP 4       // edges per wave pass (16 lanes per edge)
#define NCACHE 4    // passes whose z is register-cached (16 edges)

__device__ __forceinline__ float shflx(float v, int mask) {
    return __shfl_xor(v, mask, 64);
}

// L2-normalize each 16-wide capsule. Wave per node, lane l owns cols 2l,2l+1.
__global__ void norm_kernel(const float* __restrict__ x, float* __restrict__ xn, int n) {
    int node = (int)((blockIdx.x * blockDim.x + threadIdx.x) >> 6);
    int lane = threadIdx.x & 63;
    if (node >= n) return;
    float2 v = *reinterpret_cast<const float2*>(x + (size_t)node * DCOLS + 2 * lane);
    float sq = v.x * v.x + v.y * v.y;
    sq += shflx(sq, 1); sq += shflx(sq, 2); sq += shflx(sq, 4);
    float inv = 1.0f / fmaxf(sqrtf(sq), EPS_N);
    *reinterpret_cast<float2*>(xn + (size_t)node * DCOLS + 2 * lane) =
        make_float2(v.x * inv, v.y * inv);
}

__global__ void count_kernel(const int* __restrict__ trg, int* __restrict__ counts, int m) {
    int e = blockIdx.x * blockDim.x + threadIdx.x;
    if (e < m) atomicAdd(&counts[trg[e]], 1);
}

__global__ void scan_kernel(int* counts, int* offsets, int n, int m) {
    __shared__ int part[1024];
    int tid = threadIdx.x;
    if (tid == 0) offsets[n] = m;
    int chunk = (n + 1023) / 1024;
    int lo = tid * chunk;
    int hi = min(lo + chunk, n);
    int s = 0;
    for (int i = lo; i < hi; ++i) s += counts[i];
    part[tid] = s;
    __syncthreads();
    for (int off = 1; off < 1024; off <<= 1) {
        int t = (tid >= off) ? part[tid - off] : 0;
        __syncthreads();
        part[tid] += t;
        __syncthreads();
    }
    int run = (tid > 0) ? part[tid - 1] : 0;
    for (int i = lo; i < hi; ++i) {
        int c = counts[i];
        offsets[i] = run;
        counts[i] = run;  // scatter cursor
        run += c;
    }
}

__global__ void scatter_kernel(const int* __restrict__ src, const int* __restrict__ trg,
                               int* cursor, int* __restrict__ elist, int m) {
    int e = blockIdx.x * blockDim.x + threadIdx.x;
    if (e < m) {
        int pos = atomicAdd(&cursor[trg[e]], 1);
        elist[pos] = src[e];
    }
}

// Process one edge slot: z[8] = this lane's 8 flat cols of the edge's source row.
// Sn[q] = S value needed by this lane's q-th col. Reduces p over the capsule's
// 2 lanes (mask 1), softmax-sum over the 8 capsules (masks 2,4,8).
__device__ __forceinline__ void process_edge(const float z[8], const float Sn[8],
                                             float acc[8], bool valid) {
    float part = z[0] * Sn[0];
#pragma unroll
    for (int q = 1; q < 8; ++q) part = fmaf(z[q], Sn[q], part);
    float p = part + shflx(part, 1);
    float ex = __expf(p);   // no max-sub: |p| <= 32, safe in f32
    float zs = ex;
    zs += shflx(zs, 2); zs += shflx(zs, 4); zs += shflx(zs, 8);
    float w = valid ? ex * __builtin_amdgcn_rcpf(zs) : 0.0f;
#pragma unroll
    for (int q = 0; q < 8; ++q) acc[q] = fmaf(w, z[q], acc[q]);
}

// Wave per node. lane = 16*slot + l16. Lane owns FLAT cols 8*l16 .. 8*l16+7.
//  - c reshape (dd=16,k=8): S[j] = sum cflat[8j..8j+7]  -> S[l16] is lane-local.
//  - z reshape (k=8,dd=16): zflat[8*l16+q] = z[i=l16>>1, j=8*(l16&1)+q]
//    -> lane needs S[8*(l16&1)+q], gathered once per iteration via bpermute.
__global__ __launch_bounds__(256) void routing_kernel(
    const float* __restrict__ xn, const int* __restrict__ offsets,
    const int* __restrict__ elist, float* __restrict__ out, int n)
{
    int node = (int)((blockIdx.x * blockDim.x + threadIdx.x) >> 6);
    int lane = threadIdx.x & 63;
    if (node >= n) return;
    int l16 = lane & 15;
    int slot = lane >> 4;

    const float4* xrow = reinterpret_cast<const float4*>(xn + (size_t)node * DCOLS + 8 * l16);
    float4 xa = xrow[0], xb = xrow[1];
    float xv[8] = {xa.x, xa.y, xa.z, xa.w, xb.x, xb.y, xb.z, xb.w};
    float cc[8];
#pragma unroll
    for (int q = 0; q < 8; ++q) cc[q] = xv[q];

    int e0 = offsets[node];
    int e1 = offsets[node + 1];
    int deg = e1 - e0;

    // Register-cache z for the first NCACHE passes (z is iteration-invariant).
    float zc[NCACHE][8];
#pragma unroll
    for (int pp = 0; pp < NCACHE; ++pp) {
        if (pp * EPP < deg) {  // wave-uniform
            int eidx = e0 + pp * EPP + slot;
            int u = (eidx < e1) ? elist[eidx] : node;
            const float4* zr = reinterpret_cast<const float4*>(xn + (size_t)u * DCOLS + 8 * l16);
            float4 a = zr[0], b = zr[1];
            zc[pp][0] = a.x; zc[pp][1] = a.y; zc[pp][2] = a.z; zc[pp][3] = a.w;
            zc[pp][4] = b.x; zc[pp][5] = b.y; zc[pp][6] = b.z; zc[pp][7] = b.w;
        }
    }

    int src_base = (lane & ~15) | (8 * (l16 & 1));

    for (int t = 0; t < ROUTIT; ++t) {
        float Sl = ((cc[0] + cc[1]) + (cc[2] + cc[3])) + ((cc[4] + cc[5]) + (cc[6] + cc[7]));
        float Sn[8];
#pragma unroll
        for (int q = 0; q < 8; ++q) Sn[q] = __shfl(Sl, src_base + q, 64);

        float acc[8];
#pragma unroll
        for (int q = 0; q < 8; ++q) acc[q] = 0.0f;

#pragma unroll
        for (int pp = 0; pp < NCACHE; ++pp) {
            if (pp * EPP < deg) {
                bool valid = (e0 + pp * EPP + slot) < e1;
                process_edge(zc[pp], Sn, acc, valid);
            }
        }
        // streaming tail for high-degree nodes
        for (int eb = e0 + NCACHE * EPP; eb < e1; eb += EPP) {
            int eidx = eb + slot;
            int u = (eidx < e1) ? elist[eidx] : node;
            const float4* zr = reinterpret_cast<const float4*>(xn + (size_t)u * DCOLS + 8 * l16);
            float4 a = zr[0], b = zr[1];
            float z[8] = {a.x, a.y, a.z, a.w, b.x, b.y, b.z, b.w};
            process_edge(z, Sn, acc, eidx < e1);
        }

        // reduce acc across the 4 edge slots (XOR butterfly -> all slots hold sum)
#pragma unroll
        for (int q = 0; q < 8; ++q) {
            acc[q] += shflx(acc[q], 16);
            acc[q] += shflx(acc[q], 32);
        }
#pragma unroll
        for (int q = 0; q < 8; ++q) cc[q] = acc[q] + xv[q];

        if (t < ROUTIT - 1) {
            // capsule = 2 lanes (16 cols): lane-local sq + 1 shfl
            float sq = cc[0] * cc[0];
#pragma unroll
            for (int q = 1; q < 8; ++q) sq = fmaf(cc[q], cc[q], sq);
            sq += shflx(sq, 1);
            float inv = 1.0f / fmaxf(sqrtf(sq), EPS_N);
#pragma unroll
            for (int q = 0; q < 8; ++q) cc[q] *= inv;
        }
    }

    if (slot == 0) {
        float4* orow = reinterpret_cast<float4*>(out + (size_t)node * DCOLS + 8 * l16);
        orow[0] = make_float4(cc[0], cc[1], cc[2], cc[3]);
        orow[1] = make_float4(cc[4], cc[5], cc[6], cc[7]);
    }
}

extern "C" void kernel_launch(void* const* d_in, const int* in_sizes, int n_in,
                              void* d_out, int out_size, void* d_ws, size_t ws_size,
                              hipStream_t stream) {
    const float* x = (const float*)d_in[0];
    const int* ei = (const int*)d_in[1];
    float* out = (float*)d_out;
    int n = in_sizes[0] / DCOLS;
    int m = in_sizes[1] / 2;
    const int* src = ei;
    const int* trg = ei + m;

    char* ws = (char*)d_ws;
    float* xn = (float*)ws;       ws += (size_t)n * DCOLS * sizeof(float);
    int* offsets = (int*)ws;      ws += (size_t)(n + 1) * sizeof(int);
    int* cursor = (int*)ws;       ws += (size_t)n * sizeof(int);
    int* elist = (int*)ws;        ws += (size_t)m * sizeof(int);

    (void)hipMemsetAsync(cursor, 0, (size_t)n * sizeof(int), stream);

    norm_kernel<<<(n + 3) / 4, 256, 0, stream>>>(x, xn, n);
    count_kernel<<<(m + 255) / 256, 256, 0, stream>>>(trg, cursor, m);
    scan_kernel<<<1, 1024, 0, stream>>>(cursor, offsets, n, m);
    scatter_kernel<<<(m + 255) / 256, 256, 0, stream>>>(src, trg, cursor, elist, m);
    routing_kernel<<<(n + 3) / 4, 256, 0, stream>>>(xn, offsets, elist, out, n);
}

// Round 4
// 319.533 us; speedup vs baseline: 2.1397x; 1.2025x over previous
//
#include <hip/hip_runtime.h>
#include <math.h>

#define DCOLS 128
#define ROUTIT 6
#define EPS_N 1e-12f
#define EPP 4       // edges per wave pass (16 lanes per edge)
#define NCACHE 2    // passes with z register-cached (8 edges)
#define NUC 4       // additional passes with cached source index (up to 24 edges)

__device__ __forceinline__ float shflx(float v, int mask) {
    return __shfl_xor(v, mask, 64);
}

// L2-normalize each 16-wide capsule. Wave per node, lane l owns cols 2l,2l+1.
__global__ void norm_kernel(const float* __restrict__ x, float* __restrict__ xn, int n) {
    int node = (int)((blockIdx.x * blockDim.x + threadIdx.x) >> 6);
    int lane = threadIdx.x & 63;
    if (node >= n) return;
    float2 v = *reinterpret_cast<const float2*>(x + (size_t)node * DCOLS + 2 * lane);
    float sq = v.x * v.x + v.y * v.y;
    sq += shflx(sq, 1); sq += shflx(sq, 2); sq += shflx(sq, 4);
    float inv = 1.0f / fmaxf(sqrtf(sq), EPS_N);
    *reinterpret_cast<float2*>(xn + (size_t)node * DCOLS + 2 * lane) =
        make_float2(v.x * inv, v.y * inv);
}

// Fused count + within-node position (single atomic pass).
__global__ void count_pos_kernel(const int* __restrict__ trg, int* __restrict__ cnt,
                                 int* __restrict__ pos, int m) {
    int e = blockIdx.x * blockDim.x + threadIdx.x;
    if (e < m) pos[e] = atomicAdd(&cnt[trg[e]], 1);
}

// Single-block exclusive scan: cnt[0..n) -> offsets[0..n].
__global__ void scan_kernel(const int* __restrict__ cnt, int* __restrict__ offsets,
                            int n, int m) {
    __shared__ int part[1024];
    int tid = threadIdx.x;
    if (tid == 0) offsets[n] = m;
    int chunk = (n + 1023) / 1024;
    int lo = tid * chunk;
    int hi = min(lo + chunk, n);
    int s = 0;
    for (int i = lo; i < hi; ++i) s += cnt[i];
    part[tid] = s;
    __syncthreads();
    for (int off = 1; off < 1024; off <<= 1) {
        int t = (tid >= off) ? part[tid - off] : 0;
        __syncthreads();
        part[tid] += t;
        __syncthreads();
    }
    int run = (tid > 0) ? part[tid - 1] : 0;
    for (int i = lo; i < hi; ++i) {
        int c = cnt[i];
        offsets[i] = run;
        run += c;
    }
}

// Non-atomic placement: elist[offsets[trg]+pos] = src.
__global__ void place_kernel(const int* __restrict__ src, const int* __restrict__ trg,
                             const int* __restrict__ pos, const int* __restrict__ offsets,
                             int* __restrict__ elist, int m) {
    int e = blockIdx.x * blockDim.x + threadIdx.x;
    if (e < m) elist[offsets[trg[e]] + pos[e]] = src[e];
}

// One edge slot: z[8] = lane's 8 flat cols of the edge's source row.
// Sn[q] = S value for this lane's q-th col. p-reduce over the capsule's 2
// lanes (mask 1), softmax-sum over the 8 capsules (masks 2,4,8).
// No max-subtraction: capsules are unit vectors and |S| <= 8, so |p| <= 8.
__device__ __forceinline__ void process_edge(const float z[8], const float Sn[8],
                                             float acc[8], bool valid) {
    float part = z[0] * Sn[0];
#pragma unroll
    for (int q = 1; q < 8; ++q) part = fmaf(z[q], Sn[q], part);
    float p = part + shflx(part, 1);
    float ex = __expf(p);
    float zs = ex;
    zs += shflx(zs, 2); zs += shflx(zs, 4); zs += shflx(zs, 8);
    float w = valid ? ex * __builtin_amdgcn_rcpf(zs) : 0.0f;
#pragma unroll
    for (int q = 0; q < 8; ++q) acc[q] = fmaf(w, z[q], acc[q]);
}

// Wave per node. lane = 16*slot + l16. Lane owns FLAT cols 8*l16..8*l16+7.
// S[l16] is lane-local; p-term for flat col f uses S[f & 15].
__global__ __launch_bounds__(256, 8) void routing_kernel(
    const float* __restrict__ xn, const int* __restrict__ offsets,
    const int* __restrict__ elist, float* __restrict__ out, int n)
{
    int node = (int)((blockIdx.x * blockDim.x + threadIdx.x) >> 6);
    int lane = threadIdx.x & 63;
    if (node >= n) return;
    int l16 = lane & 15;
    int slot = lane >> 4;

    const float4* xrow = reinterpret_cast<const float4*>(xn + (size_t)node * DCOLS + 8 * l16);
    float4 xa = xrow[0], xb = xrow[1];
    float xv[8] = {xa.x, xa.y, xa.z, xa.w, xb.x, xb.y, xb.z, xb.w};
    float cc[8];
#pragma unroll
    for (int q = 0; q < 8; ++q) cc[q] = xv[q];

    int e0 = offsets[node];
    int e1 = offsets[node + 1];
    int deg = e1 - e0;

    // z register cache for the first NCACHE passes (z is iteration-invariant).
    float zc[NCACHE][8];
#pragma unroll
    for (int pp = 0; pp < NCACHE; ++pp) {
        if (pp * EPP < deg) {  // wave-uniform
            int eidx = e0 + pp * EPP + slot;
            int u = (eidx < e1) ? elist[eidx] : node;
            const float4* zr = reinterpret_cast<const float4*>(xn + (size_t)u * DCOLS + 8 * l16);
            float4 a = zr[0], b = zr[1];
            zc[pp][0] = a.x; zc[pp][1] = a.y; zc[pp][2] = a.z; zc[pp][3] = a.w;
            zc[pp][4] = b.x; zc[pp][5] = b.y; zc[pp][6] = b.z; zc[pp][7] = b.w;
        }
    }
    // source-index cache for the next NUC passes (z streamed from L2/L3).
    int uc[NUC];
#pragma unroll
    for (int pp = 0; pp < NUC; ++pp) {
        if ((NCACHE + pp) * EPP < deg) {
            int eidx = e0 + (NCACHE + pp) * EPP + slot;
            uc[pp] = (eidx < e1) ? elist[eidx] : node;
        }
    }

    int src_base = (lane & ~15) | (8 * (l16 & 1));

    for (int t = 0; t < ROUTIT; ++t) {
        // S[l16] lane-local, then broadcast the 8 values this lane needs
        float Sl = ((cc[0] + cc[1]) + (cc[2] + cc[3])) + ((cc[4] + cc[5]) + (cc[6] + cc[7]));
        float Sn[8];
#pragma unroll
        for (int q = 0; q < 8; ++q) Sn[q] = __shfl(Sl, src_base + q, 64);

        float acc[8];
#pragma unroll
        for (int q = 0; q < 8; ++q) acc[q] = 0.0f;

#pragma unroll
        for (int pp = 0; pp < NCACHE; ++pp) {
            if (pp * EPP < deg) {
                bool valid = (e0 + pp * EPP + slot) < e1;
                process_edge(zc[pp], Sn, acc, valid);
            }
        }
#pragma unroll
        for (int pp = 0; pp < NUC; ++pp) {
            if ((NCACHE + pp) * EPP < deg) {
                bool valid = (e0 + (NCACHE + pp) * EPP + slot) < e1;
                const float4* zr =
                    reinterpret_cast<const float4*>(xn + (size_t)uc[pp] * DCOLS + 8 * l16);
                float4 a = zr[0], b = zr[1];
                float z[8] = {a.x, a.y, a.z, a.w, b.x, b.y, b.z, b.w};
                process_edge(z, Sn, acc, valid);
            }
        }
        // streaming tail for very-high-degree nodes (P ~ 0.1%)
        for (int eb = e0 + (NCACHE + NUC) * EPP; eb < e1; eb += EPP) {
            int eidx = eb + slot;
            int u = (eidx < e1) ? elist[eidx] : node;
            const float4* zr = reinterpret_cast<const float4*>(xn + (size_t)u * DCOLS + 8 * l16);
            float4 a = zr[0], b = zr[1];
            float z[8] = {a.x, a.y, a.z, a.w, b.x, b.y, b.z, b.w};
            process_edge(z, Sn, acc, eidx < e1);
        }

        // reduce across the 4 edge slots
#pragma unroll
        for (int q = 0; q < 8; ++q) {
            acc[q] += shflx(acc[q], 16);
            acc[q] += shflx(acc[q], 32);
        }
#pragma unroll
        for (int q = 0; q < 8; ++q) cc[q] = acc[q] + xv[q];

        if (t < ROUTIT - 1) {
            float sq = cc[0] * cc[0];
#pragma unroll
            for (int q = 1; q < 8; ++q) sq = fmaf(cc[q], cc[q], sq);
            sq += shflx(sq, 1);   // capsule = 2 lanes
            float inv = 1.0f / fmaxf(sqrtf(sq), EPS_N);
#pragma unroll
            for (int q = 0; q < 8; ++q) cc[q] *= inv;
        }
    }

    if (slot == 0) {
        float4* orow = reinterpret_cast<float4*>(out + (size_t)node * DCOLS + 8 * l16);
        orow[0] = make_float4(cc[0], cc[1], cc[2], cc[3]);
        orow[1] = make_float4(cc[4], cc[5], cc[6], cc[7]);
    }
}

extern "C" void kernel_launch(void* const* d_in, const int* in_sizes, int n_in,
                              void* d_out, int out_size, void* d_ws, size_t ws_size,
                              hipStream_t stream) {
    const float* x = (const float*)d_in[0];
    const int* ei = (const int*)d_in[1];
    float* out = (float*)d_out;
    int n = in_sizes[0] / DCOLS;
    int m = in_sizes[1] / 2;
    const int* src = ei;
    const int* trg = ei + m;

    char* ws = (char*)d_ws;
    float* xn = (float*)ws;       ws += (size_t)n * DCOLS * sizeof(float);
    int* offsets = (int*)ws;      ws += (size_t)(n + 1) * sizeof(int);
    int* cnt = (int*)ws;          ws += (size_t)n * sizeof(int);
    int* pos = (int*)ws;          ws += (size_t)m * sizeof(int);
    int* elist = (int*)ws;        ws += (size_t)m * sizeof(int);

    (void)hipMemsetAsync(cnt, 0, (size_t)n * sizeof(int), stream);

    norm_kernel<<<(n + 3) / 4, 256, 0, stream>>>(x, xn, n);
    count_pos_kernel<<<(m + 255) / 256, 256, 0, stream>>>(trg, cnt, pos, m);
    scan_kernel<<<1, 1024, 0, stream>>>(cnt, offsets, n, m);
    place_kernel<<<(m + 255) / 256, 256, 0, stream>>>(src, trg, pos, offsets, elist, m);
    routing_kernel<<<(n + 3) / 4, 256, 0, stream>>>(xn, offsets, elist, out, n);
}